// Round 5
// baseline (778.439 us; speedup 1.0000x reference)
//
#include <hip/hip_runtime.h>

typedef __attribute__((ext_vector_type(8))) short short8;
typedef __attribute__((ext_vector_type(4))) float f32x4;
typedef unsigned short ushort_t;
typedef unsigned int uint_t;

#define MFMA16(a, b, c) __builtin_amdgcn_mfma_f32_16x16x32_bf16((a), (b), (c), 0, 0, 0)
#define SCALE_Q 0.17677669529663687f

__device__ __forceinline__ ushort_t f2bf(float f) {
    union { float f; uint_t u; } c; c.f = f;
    uint_t u = c.u;
    uint_t r = (u + 0x7FFFu + ((u >> 16) & 1u)) >> 16;
    return (ushort_t)r;
}
__device__ __forceinline__ uint_t pack2(float a, float b) {
    return (uint_t)f2bf(a) | ((uint_t)f2bf(b) << 16);
}
__device__ __forceinline__ float bf2f(ushort_t u) {
    union { float f; uint_t x; } c; c.x = ((uint_t)u) << 16; return c.f;
}

// ---------------------------------------------------------------------------
// Kernel 1: DPB MLP -> dpb_vals[289]. One point per wave, lanes = 64 channels.
// ---------------------------------------------------------------------------
__device__ __forceinline__ float wredsum(float v) {
    #pragma unroll
    for (int m = 1; m < 64; m <<= 1) v += __shfl_xor(v, m);
    return v;
}

__global__ void dpb_vals_kernel(const float* __restrict__ w1, const float* __restrict__ b1,
                                const float* __restrict__ g1, const float* __restrict__ be1,
                                const float* __restrict__ w2, const float* __restrict__ b2,
                                const float* __restrict__ g2, const float* __restrict__ be2,
                                const float* __restrict__ w3, const float* __restrict__ b3,
                                const float* __restrict__ g3, const float* __restrict__ be3,
                                const float* __restrict__ w4, const float* __restrict__ b4,
                                float* __restrict__ valsg) {
    int wv = threadIdx.x >> 6, j = threadIdx.x & 63;
    int pt = blockIdx.x * 8 + wv;
    if (pt >= 289) return;
    float ri = (float)(pt / 17 - 8), rj = (float)(pt % 17 - 8);

    float t = ri * w1[2 * j] + rj * w1[2 * j + 1] + b1[j];
    float mu = wredsum(t) * (1.f / 64.f);
    float d = t - mu;
    float var = wredsum(d * d) * (1.f / 64.f);
    float h = fmaxf(0.f, d * rsqrtf(var + 1e-5f) * g1[j] + be1[j]);

    float a = b2[j];
    for (int k = 0; k < 64; ++k) a += __shfl(h, k) * w2[j * 64 + k];
    mu = wredsum(a) * (1.f / 64.f);
    d = a - mu;
    var = wredsum(d * d) * (1.f / 64.f);
    h = fmaxf(0.f, d * rsqrtf(var + 1e-5f) * g2[j] + be2[j]);

    a = b3[j];
    for (int k = 0; k < 64; ++k) a += __shfl(h, k) * w3[j * 64 + k];
    mu = wredsum(a) * (1.f / 64.f);
    d = a - mu;
    var = wredsum(d * d) * (1.f / 64.f);
    h = fmaxf(0.f, d * rsqrtf(var + 1e-5f) * g3[j] + be3[j]);

    float v = wredsum(h * w4[j]) + b4[0];
    if (j == 0) valsg[pt] = v;
}

// ---------------------------------------------------------------------------
// Kernel 2: permute+scale+convert weights to bf16, build biasR register table.
// wbf qkv rows permuted: wave wv row s (0..95): s<32 -> Q head wv (scaled),
// s<64 -> K head wv, else V head wv.
// biasR[l*64 + nts*16 + mts*4 + e] = bias[i = nts*16+(l&15)][j = mts*16+(l>>4)*4+e]
// ---------------------------------------------------------------------------
__global__ void cvt_kernel(const float* __restrict__ wqkv, const float* __restrict__ wout,
                           const float* __restrict__ valsg,
                           ushort_t* __restrict__ wbf, float* __restrict__ biasR) {
    int i = blockIdx.x * 512 + threadIdx.x;   // grid 520 -> 266240 threads
    if (i < 196608) {
        int r = i >> 8, c = i & 255;
        int wv = r / 96, s = r % 96;
        int src = (s < 32) ? (wv * 32 + s) : (s < 64) ? (256 + wv * 32 + s - 32)
                                                      : (512 + wv * 32 + s - 64);
        float f = wqkv[src * 256 + c];
        if (s < 32) f *= SCALE_Q;
        wbf[i] = f2bf(f);
    } else if (i < 262144) {
        wbf[i] = f2bf(wout[i - 196608]);
    } else {
        int idx = i - 262144;                 // < 4096
        int l = idx >> 6, r6 = idx & 63;
        int nts = r6 >> 4, mts = (r6 >> 2) & 3, e = r6 & 3;
        int ii = nts * 16 + (l & 15);
        int jj = mts * 16 + ((l >> 4) << 2) + e;
        int p = ((ii >> 3) - (jj >> 3) + 7) * 15 + ((ii & 7) - (jj & 7) + 7);
        biasR[idx] = valsg[p];
    }
}

// ---------------------------------------------------------------------------
// Main fused kernel. 512 thr (8 waves), one window per block, 2 blocks/CU.
// LDS (70144 B):
//   [0,     32768) : Xs bf16 [256 d][64 n] swz (^(d&7)<<4)   -> later V: 8 x [32 d][64 j] swz
//   [32768, 65536) : XN bf16 [64 n][512B] swz (^(n&7)<<4)    -> later K: 8 x [64 j][32 dh] ; later OT
//   [65536, 69632) : red f32 [2][8][64]
//   [69632, 70144) : muv f32 [2][64]
// ---------------------------------------------------------------------------
#define LDS_BYTES 70144

__global__ __launch_bounds__(512, 4) void win_attn(
    const float* __restrict__ x, const float* __restrict__ gamw, const float* __restrict__ betw,
    const ushort_t* __restrict__ wqkv, const ushort_t* __restrict__ wout,
    const float* __restrict__ boutp, const float* __restrict__ biasR,
    float* __restrict__ outp) {
    extern __shared__ char smem[];
    const int tid = threadIdx.x;
    // XCD swizzle: 2048 blocks, 8 XCDs -> contiguous 256-window chunks per XCD
    const int wid = ((blockIdx.x & 7) << 8) | (blockIdx.x >> 3);
    const int bb = wid >> 10, rem = wid & 1023, wh = rem >> 5, ww = rem & 31;
    const int xoff = bb * 16777216 + wh * 2048 + ww * 8;
    const float* xb = x + xoff;

    char* Xs  = smem;                 // region0
    char* XNb = smem + 32768;         // region1
    float* red = (float*)(smem + 65536);
    float* muv = (float*)(smem + 69632);

    const int wv = tid >> 6, l = tid & 63, g = l >> 4, m15 = l & 15;

    // ---- phase 1: load window -> Xs bf16 [256][64] swz ----
    #pragma unroll
    for (int it = 0; it < 8; ++it) {
        int idx = it * 512 + tid;
        int d = idx >> 4, p4 = idx & 15;
        int py = p4 >> 1, c4 = (p4 & 1) << 2;
        float4 v = *(const float4*)(xb + d * 65536 + py * 256 + c4);
        uint2 w; w.x = pack2(v.x, v.y); w.y = pack2(v.z, v.w);
        int bo = (d * 128 + (py * 8 + c4) * 2) ^ ((d & 7) << 4);
        *(uint2*)(Xs + bo) = w;
    }
    __syncthreads();

    // ---- phase 2: channel-LN stats ----
    {
        int n = l, dq = wv;
        float s = 0.f, s2 = 0.f;
        #pragma unroll
        for (int i2 = 0; i2 < 32; ++i2) {
            int d = dq * 32 + i2;
            float v = bf2f(*(const ushort_t*)(Xs + ((d * 128 + n * 2) ^ ((d & 7) << 4))));
            s += v; s2 += v * v;
        }
        red[dq * 64 + n] = s;
        red[512 + dq * 64 + n] = s2;
    }
    __syncthreads();
    if (tid < 64) {
        float s = 0.f, s2 = 0.f;
        #pragma unroll
        for (int q = 0; q < 8; ++q) { s += red[q * 64 + tid]; s2 += red[512 + q * 64 + tid]; }
        float mu = s * 0.00390625f;
        float var = s2 * 0.00390625f - mu * mu;
        muv[tid] = mu;
        muv[64 + tid] = rsqrtf(var + 1e-5f);
    }
    __syncthreads();

    // ---- normalize -> XN[n][d] bf16 (swizzled) ----
    {
        int n = l, dc = wv;
        float mu = muv[n], rs = muv[64 + n];
        #pragma unroll
        for (int jj = 0; jj < 4; ++jj) {
            int d0 = dc * 32 + jj * 8;
            uint_t p[4];
            #pragma unroll
            for (int h = 0; h < 4; ++h) {
                int da = d0 + 2 * h, db = d0 + 2 * h + 1;
                float va = bf2f(*(const ushort_t*)(Xs + ((da * 128 + n * 2) ^ ((da & 7) << 4))));
                float vb = bf2f(*(const ushort_t*)(Xs + ((db * 128 + n * 2) ^ ((db & 7) << 4))));
                float aa = (va - mu) * rs * gamw[da] + betw[da];
                float ab = (vb - mu) * rs * gamw[db] + betw[db];
                p[h] = pack2(aa, ab);
            }
            int bo = ((n << 9) + (d0 << 1));
            bo ^= ((bo >> 9) & 7) << 4;
            uint4 q4; q4.x = p[0]; q4.y = p[1]; q4.z = p[2]; q4.w = p[3];
            *(uint4*)(XNb + bo) = q4;
        }
    }
    __syncthreads();

    // ---- phase 3: QKV GEMM. Wave wv = head wv: rows 0-31 Q, 32-63 K, 64-95 V ----
    f32x4 acc[6][4] = {};
    for (int kt = 0; kt < 8; ++kt) {
        short8 bfr[4];
        #pragma unroll
        for (int nt = 0; nt < 4; ++nt) {
            int bo = ((nt * 16 + m15) << 9) + kt * 64 + g * 16;
            bo ^= ((bo >> 9) & 7) << 4;
            bfr[nt] = *(const short8*)(XNb + bo);
        }
        #pragma unroll
        for (int mt = 0; mt < 6; ++mt) {
            short8 afr = *(const short8*)(wqkv + (wv * 96 + mt * 16 + m15) * 256 + kt * 32 + g * 8);
            #pragma unroll
            for (int nt = 0; nt < 4; ++nt)
                acc[mt][nt] = MFMA16(afr, bfr[nt], acc[mt][nt]);
        }
    }
    __syncthreads();   // XN dead -> region1 becomes K; region0 (Xs dead) becomes V

    char* Ksh = XNb + wv * 4096;   // [64 j][32 dh] bf16, row 64 B (conflict-free frag reads)
    char* Vsh = Xs  + wv * 4096;   // [32 d][64 j] bf16, row 128 B, swz ^(d&7)<<4

    // scatter K
    #pragma unroll
    for (int mtk = 0; mtk < 2; ++mtk)
        #pragma unroll
        for (int nt = 0; nt < 4; ++nt) {
            int j = nt * 16 + m15;
            uint2 w; w.x = pack2(acc[2 + mtk][nt][0], acc[2 + mtk][nt][1]);
                     w.y = pack2(acc[2 + mtk][nt][2], acc[2 + mtk][nt][3]);
            *(uint2*)(Ksh + j * 64 + (mtk * 16 + g * 4) * 2) = w;
        }
    // scatter V
    #pragma unroll
    for (int mtv = 0; mtv < 2; ++mtv)
        #pragma unroll
        for (int nt = 0; nt < 4; ++nt)
            #pragma unroll
            for (int e = 0; e < 4; ++e) {
                int d = mtv * 16 + g * 4 + e;
                int bo = (d * 128 + (nt * 16 + m15) * 2) ^ ((d & 7) << 4);
                *(ushort_t*)(Vsh + bo) = f2bf(acc[4 + mtv][nt][e]);
            }

    // build Q B-frags from acc[0..1] via shuffles: qf[t] elem jj = Q[i=t*16+m15][dh=g*8+jj]
    const int srcA = (((2 * g) & 3) << 4) | m15;
    const int srcB = (((2 * g + 1) & 3) << 4) | m15;
    const bool hi = (g >= 2);
    union F8 { short8 v; uint_t u[4]; };
    F8 qf[4];
    #pragma unroll
    for (int t = 0; t < 4; ++t) {
        uint_t a0 = pack2(acc[0][t][0], acc[0][t][1]);
        uint_t a1 = pack2(acc[0][t][2], acc[0][t][3]);
        uint_t b0 = pack2(acc[1][t][0], acc[1][t][1]);
        uint_t b1 = pack2(acc[1][t][2], acc[1][t][3]);
        uint_t wA0 = __shfl(a0, srcA), wA1 = __shfl(a1, srcA);
        uint_t wB0 = __shfl(a0, srcB), wB1 = __shfl(a1, srcB);
        uint_t xA0 = __shfl(b0, srcA), xA1 = __shfl(b1, srcA);
        uint_t xB0 = __shfl(b0, srcB), xB1 = __shfl(b1, srcB);
        qf[t].u[0] = hi ? xA0 : wA0;
        qf[t].u[1] = hi ? xA1 : wA1;
        qf[t].u[2] = hi ? xB0 : wB0;
        qf[t].u[3] = hi ? xB1 : wB1;
    }

    // ---- sim^T = K . Q^T : s[mts][nts] = C[j = mts*16+g*4+e][i = nts*16+m15] ----
    f32x4 s[4][4];
    {
        short8 kfr[4];
        #pragma unroll
        for (int mts = 0; mts < 4; ++mts)
            kfr[mts] = *(const short8*)(Ksh + (mts * 16 + m15) * 64 + g * 16);
        #pragma unroll
        for (int mts = 0; mts < 4; ++mts)
            #pragma unroll
            for (int nts = 0; nts < 4; ++nts) {
                f32x4 z = {};
                s[mts][nts] = MFMA16(kfr[mts], qf[nts].v, z);
            }
    }

    // ---- bias + softmax over j (j lives in regs (mts,e) x lane-groups g) ----
    #pragma unroll
    for (int nts = 0; nts < 4; ++nts) {
        const float* brp = biasR + l * 64 + nts * 16;
        float4 br0 = *(const float4*)(brp);
        float4 br1 = *(const float4*)(brp + 4);
        float4 br2 = *(const float4*)(brp + 8);
        float4 br3 = *(const float4*)(brp + 12);
        s[0][nts][0] += br0.x; s[0][nts][1] += br0.y; s[0][nts][2] += br0.z; s[0][nts][3] += br0.w;
        s[1][nts][0] += br1.x; s[1][nts][1] += br1.y; s[1][nts][2] += br1.z; s[1][nts][3] += br1.w;
        s[2][nts][0] += br2.x; s[2][nts][1] += br2.y; s[2][nts][2] += br2.z; s[2][nts][3] += br2.w;
        s[3][nts][0] += br3.x; s[3][nts][1] += br3.y; s[3][nts][2] += br3.z; s[3][nts][3] += br3.w;

        float mx = s[0][nts][0];
        #pragma unroll
        for (int mts = 0; mts < 4; ++mts)
            #pragma unroll
            for (int e = 0; e < 4; ++e) mx = fmaxf(mx, s[mts][nts][e]);
        mx = fmaxf(mx, __shfl_xor(mx, 16));
        mx = fmaxf(mx, __shfl_xor(mx, 32));
        float sum = 0.f;
        #pragma unroll
        for (int mts = 0; mts < 4; ++mts)
            #pragma unroll
            for (int e = 0; e < 4; ++e) {
                float p = __expf(s[mts][nts][e] - mx);
                s[mts][nts][e] = p; sum += p;
            }
        sum += __shfl_xor(sum, 16);
        sum += __shfl_xor(sum, 32);
        float inv = 1.f / sum;
        #pragma unroll
        for (int mts = 0; mts < 4; ++mts)
            #pragma unroll
            for (int e = 0; e < 4; ++e) s[mts][nts][e] *= inv;
    }

    // ---- PV: O^T[d][i] = sum_j V[d][j] * P[i][j] ----
    f32x4 o2[2][4] = {};
    #pragma unroll
    for (int ks = 0; ks < 2; ++ks) {
        // build P B-frags: pb[t] elem jj = P[i=t*16+m15][j = ks*32+g*8+jj]
        F8 pb[4];
        #pragma unroll
        for (int t = 0; t < 4; ++t) {
            uint_t a0 = pack2(s[ks * 2 + 0][t][0], s[ks * 2 + 0][t][1]);
            uint_t a1 = pack2(s[ks * 2 + 0][t][2], s[ks * 2 + 0][t][3]);
            uint_t b0 = pack2(s[ks * 2 + 1][t][0], s[ks * 2 + 1][t][1]);
            uint_t b1 = pack2(s[ks * 2 + 1][t][2], s[ks * 2 + 1][t][3]);
            uint_t wA0 = __shfl(a0, srcA), wA1 = __shfl(a1, srcA);
            uint_t wB0 = __shfl(a0, srcB), wB1 = __shfl(a1, srcB);
            uint_t xA0 = __shfl(b0, srcA), xA1 = __shfl(b1, srcA);
            uint_t xB0 = __shfl(b0, srcB), xB1 = __shfl(b1, srcB);
            pb[t].u[0] = hi ? xA0 : wA0;
            pb[t].u[1] = hi ? xA1 : wA1;
            pb[t].u[2] = hi ? xB0 : wB0;
            pb[t].u[3] = hi ? xB1 : wB1;
        }
        #pragma unroll
        for (int mt2 = 0; mt2 < 2; ++mt2) {
            int d = mt2 * 16 + m15;
            int vo = (d * 128 + ks * 64 + g * 16) ^ ((d & 7) << 4);
            short8 va = *(const short8*)(Vsh + vo);
            #pragma unroll
            for (int t = 0; t < 4; ++t)
                o2[mt2][t] = MFMA16(va, pb[t].v, o2[mt2][t]);
        }
    }

    __syncthreads();   // all K frag reads done -> region1 becomes OT

    // write OT[i][o = wv*32 + d] bf16 into region1 (swizzled)
    #pragma unroll
    for (int mt2 = 0; mt2 < 2; ++mt2)
        #pragma unroll
        for (int t = 0; t < 4; ++t) {
            int i = t * 16 + m15;
            int dd = wv * 32 + mt2 * 16 + g * 4;
            int bo = (i << 9) + (dd << 1);
            bo ^= ((bo >> 9) & 7) << 4;
            uint2 pv;
            pv.x = pack2(o2[mt2][t][0], o2[mt2][t][1]);
            pv.y = pack2(o2[mt2][t][2], o2[mt2][t][3]);
            *(uint2*)(XNb + bo) = pv;
        }
    __syncthreads();

    // ---- phase 5: out projection + store ----
    {
        f32x4 po[2][4] = {};
        for (int kt = 0; kt < 8; ++kt) {
            short8 bfr[4];
            #pragma unroll
            for (int nt = 0; nt < 4; ++nt) {
                int bo = ((nt * 16 + m15) << 9) + kt * 64 + g * 16;
                bo ^= ((bo >> 9) & 7) << 4;
                bfr[nt] = *(const short8*)(XNb + bo);
            }
            #pragma unroll
            for (int mt = 0; mt < 2; ++mt) {
                short8 afr = *(const short8*)(wout + (wv * 32 + mt * 16 + m15) * 256 + kt * 32 + g * 8);
                #pragma unroll
                for (int nt = 0; nt < 4; ++nt)
                    po[mt][nt] = MFMA16(afr, bfr[nt], po[mt][nt]);
            }
        }
        float* ob = outp + xoff;
        #pragma unroll
        for (int mt = 0; mt < 2; ++mt) {
            int o0 = wv * 32 + mt * 16 + g * 4;
            float bo0 = boutp[o0], bo1 = boutp[o0 + 1], bo2 = boutp[o0 + 2], bo3 = boutp[o0 + 3];
            #pragma unroll
            for (int nt = 0; nt < 4; ++nt) {
                int i = nt * 16 + m15;
                int pix = (i >> 3) * 256 + (i & 7);
                ob[(o0 + 0) * 65536 + pix] = po[mt][nt][0] + bo0;
                ob[(o0 + 1) * 65536 + pix] = po[mt][nt][1] + bo1;
                ob[(o0 + 2) * 65536 + pix] = po[mt][nt][2] + bo2;
                ob[(o0 + 3) * 65536 + pix] = po[mt][nt][3] + bo3;
            }
        }
    }
}

// ---------------------------------------------------------------------------
extern "C" void kernel_launch(void* const* d_in, const int* in_sizes, int n_in,
                              void* d_out, int out_size, void* d_ws, size_t ws_size,
                              hipStream_t stream) {
    const float* x     = (const float*)d_in[0];
    const float* g     = (const float*)d_in[1];
    const float* b     = (const float*)d_in[2];
    const float* w_qkv = (const float*)d_in[3];
    const float* w_out = (const float*)d_in[4];
    const float* b_out = (const float*)d_in[5];
    const float* dw1 = (const float*)d_in[6],  *db1 = (const float*)d_in[7];
    const float* dg1 = (const float*)d_in[8],  *dbe1 = (const float*)d_in[9];
    const float* dw2 = (const float*)d_in[10], *db2 = (const float*)d_in[11];
    const float* dg2 = (const float*)d_in[12], *dbe2 = (const float*)d_in[13];
    const float* dw3 = (const float*)d_in[14], *db3 = (const float*)d_in[15];
    const float* dg3 = (const float*)d_in[16], *dbe3 = (const float*)d_in[17];
    const float* dw4 = (const float*)d_in[18], *db4 = (const float*)d_in[19];

    ushort_t* wbf   = (ushort_t*)d_ws;                         // 262144 bf16 = 524288 B
    float*    biasR = (float*)((char*)d_ws + 524288);          // 4096 f32   = 16384 B
    float*    valsg = (float*)((char*)d_ws + 540672);          // 289 f32

    hipLaunchKernelGGL(dpb_vals_kernel, dim3(37), dim3(512), 0, stream,
                       dw1, db1, dg1, dbe1, dw2, db2, dg2, dbe2,
                       dw3, db3, dg3, dbe3, dw4, db4, valsg);
    hipLaunchKernelGGL(cvt_kernel, dim3(520), dim3(512), 0, stream,
                       w_qkv, w_out, valsg, wbf, biasR);

    (void)hipFuncSetAttribute((const void*)win_attn,
                              hipFuncAttributeMaxDynamicSharedMemorySize, LDS_BYTES);
    hipLaunchKernelGGL(win_attn, dim3(2048), dim3(512), LDS_BYTES, stream,
                       x, g, b, wbf, wbf + 196608, b_out, biasR, (float*)d_out);
}

// Round 7
// 698.663 us; speedup vs baseline: 1.1142x; 1.1142x over previous
//
#include <hip/hip_runtime.h>

typedef __attribute__((ext_vector_type(8))) short short8;
typedef __attribute__((ext_vector_type(4))) float f32x4;
typedef unsigned short ushort_t;
typedef unsigned int uint_t;

#define MFMA16(a, b, c) __builtin_amdgcn_mfma_f32_16x16x32_bf16((a), (b), (c), 0, 0, 0)
#define SCALE_Q 0.17677669529663687f

__device__ __forceinline__ ushort_t f2bf(float f) {
    union { float f; uint_t u; } c; c.f = f;
    uint_t u = c.u;
    uint_t r = (u + 0x7FFFu + ((u >> 16) & 1u)) >> 16;
    return (ushort_t)r;
}
__device__ __forceinline__ uint_t pack2(float a, float b) {
    return (uint_t)f2bf(a) | ((uint_t)f2bf(b) << 16);
}
__device__ __forceinline__ float bf2f(ushort_t u) {
    union { float f; uint_t x; } c; c.x = ((uint_t)u) << 16; return c.f;
}

union F8 { short8 v; uint_t u[4]; };

// Build an MFMA A- or B-fragment (lane l, elem q -> M[row/col=l&15][k=(l>>4)*8+q])
// from two accumulator rows holding M^T (acc[c][t][e] = M[c*16+g*4+e][t*16+m15]).
__device__ __forceinline__ void build_frag(const f32x4* accLo, const f32x4* accHi,
                                           int srcA, int srcB, bool hi, F8* out) {
    #pragma unroll
    for (int t = 0; t < 4; ++t) {
        uint_t a0 = pack2(accLo[t][0], accLo[t][1]);
        uint_t a1 = pack2(accLo[t][2], accLo[t][3]);
        uint_t b0 = pack2(accHi[t][0], accHi[t][1]);
        uint_t b1 = pack2(accHi[t][2], accHi[t][3]);
        uint_t wA0 = __shfl(a0, srcA), wA1 = __shfl(a1, srcA);
        uint_t wB0 = __shfl(a0, srcB), wB1 = __shfl(a1, srcB);
        uint_t xA0 = __shfl(b0, srcA), xA1 = __shfl(b1, srcA);
        uint_t xB0 = __shfl(b0, srcB), xB1 = __shfl(b1, srcB);
        out[t].u[0] = hi ? xA0 : wA0;
        out[t].u[1] = hi ? xA1 : wA1;
        out[t].u[2] = hi ? xB0 : wB0;
        out[t].u[3] = hi ? xB1 : wB1;
    }
}

// ---------------------------------------------------------------------------
// Kernel 1: DPB MLP -> dpb_vals[289]. One point per wave, lanes = 64 channels.
// ---------------------------------------------------------------------------
__device__ __forceinline__ float wredsum(float v) {
    #pragma unroll
    for (int m = 1; m < 64; m <<= 1) v += __shfl_xor(v, m);
    return v;
}

__global__ void dpb_vals_kernel(const float* __restrict__ w1, const float* __restrict__ b1,
                                const float* __restrict__ g1, const float* __restrict__ be1,
                                const float* __restrict__ w2, const float* __restrict__ b2,
                                const float* __restrict__ g2, const float* __restrict__ be2,
                                const float* __restrict__ w3, const float* __restrict__ b3,
                                const float* __restrict__ g3, const float* __restrict__ be3,
                                const float* __restrict__ w4, const float* __restrict__ b4,
                                float* __restrict__ valsg) {
    int wv = threadIdx.x >> 6, j = threadIdx.x & 63;
    int pt = blockIdx.x * 8 + wv;
    if (pt >= 289) return;
    float ri = (float)(pt / 17 - 8), rj = (float)(pt % 17 - 8);

    float t = ri * w1[2 * j] + rj * w1[2 * j + 1] + b1[j];
    float mu = wredsum(t) * (1.f / 64.f);
    float d = t - mu;
    float var = wredsum(d * d) * (1.f / 64.f);
    float h = fmaxf(0.f, d * rsqrtf(var + 1e-5f) * g1[j] + be1[j]);

    float a = b2[j];
    for (int k = 0; k < 64; ++k) a += __shfl(h, k) * w2[j * 64 + k];
    mu = wredsum(a) * (1.f / 64.f);
    d = a - mu;
    var = wredsum(d * d) * (1.f / 64.f);
    h = fmaxf(0.f, d * rsqrtf(var + 1e-5f) * g2[j] + be2[j]);

    a = b3[j];
    for (int k = 0; k < 64; ++k) a += __shfl(h, k) * w3[j * 64 + k];
    mu = wredsum(a) * (1.f / 64.f);
    d = a - mu;
    var = wredsum(d * d) * (1.f / 64.f);
    h = fmaxf(0.f, d * rsqrtf(var + 1e-5f) * g3[j] + be3[j]);

    float v = wredsum(h * w4[j]) + b4[0];
    if (j == 0) valsg[pt] = v;
}

// ---------------------------------------------------------------------------
// Kernel 2: permute+scale+convert weights to bf16, build biasR register table.
// wbf qkv rows permuted: wave wv row s (0..95): s<32 -> Q head wv (scaled),
// s<64 -> K head wv, else V head wv.
// biasR[l*64 + nts*16 + mts*4 + e] = bias[i = nts*16+(l&15)][j = mts*16+(l>>4)*4+e]
// ---------------------------------------------------------------------------
__global__ void cvt_kernel(const float* __restrict__ wqkv, const float* __restrict__ wout,
                           const float* __restrict__ valsg,
                           ushort_t* __restrict__ wbf, float* __restrict__ biasR) {
    int i = blockIdx.x * 512 + threadIdx.x;   // grid 520 -> 266240 threads
    if (i < 196608) {
        int r = i >> 8, c = i & 255;
        int wv = r / 96, s = r % 96;
        int src = (s < 32) ? (wv * 32 + s) : (s < 64) ? (256 + wv * 32 + s - 32)
                                                      : (512 + wv * 32 + s - 64);
        float f = wqkv[src * 256 + c];
        if (s < 32) f *= SCALE_Q;
        wbf[i] = f2bf(f);
    } else if (i < 262144) {
        wbf[i] = f2bf(wout[i - 196608]);
    } else {
        int idx = i - 262144;                 // < 4096
        int l = idx >> 6, r6 = idx & 63;
        int nts = r6 >> 4, mts = (r6 >> 2) & 3, e = r6 & 3;
        int ii = nts * 16 + (l & 15);
        int jj = mts * 16 + ((l >> 4) << 2) + e;
        int p = ((ii >> 3) - (jj >> 3) + 7) * 15 + ((ii & 7) - (jj & 7) + 7);
        biasR[idx] = valsg[p];
    }
}

// ---------------------------------------------------------------------------
// Main fused kernel. 512 thr (8 waves), one window per block, 2 blocks/CU.
// Register-pressure plan: QKV GEMM split into pass A (Q+K, 64 acc regs) and
// pass B (V, 32 acc regs); Q and K fragments live in registers (shuffle-built,
// never touch LDS); only V round-trips through LDS (per-wave-private chunk).
// LDS (70144 B):
//   [0,     32768) : Xs bf16 [256 d][64 n] swz (^(d&7)<<4)  -> later V: 8 x [32 d][64 j] swz
//   [32768, 65536) : XN bf16 [64 n][512B] swz (^(n&7)<<4)   -> later OT
//   [65536, 69632) : red f32 [2][8][64]
//   [69632, 70144) : muv f32 [2][64]
// ---------------------------------------------------------------------------
#define LDS_BYTES 70144

__global__ __launch_bounds__(512, 4) void win_attn(
    const float* __restrict__ x, const float* __restrict__ gamw, const float* __restrict__ betw,
    const ushort_t* __restrict__ wqkv, const ushort_t* __restrict__ wout,
    const float* __restrict__ boutp, const float* __restrict__ biasR,
    float* __restrict__ outp) {
    extern __shared__ char smem[];
    const int tid = threadIdx.x;
    // XCD swizzle: 2048 blocks, 8 XCDs -> contiguous 256-window chunks per XCD
    const int wid = ((blockIdx.x & 7) << 8) | (blockIdx.x >> 3);
    const int bb = wid >> 10, rem = wid & 1023, wh = rem >> 5, ww = rem & 31;
    const int xoff = bb * 16777216 + wh * 2048 + ww * 8;
    const float* xb = x + xoff;

    char* Xs  = smem;                 // region0
    char* XNb = smem + 32768;         // region1
    float* red = (float*)(smem + 65536);
    float* muv = (float*)(smem + 69632);

    const int wv = tid >> 6, l = tid & 63, g = l >> 4, m15 = l & 15;

    // ---- phase 1: load window -> Xs bf16 [256][64] swz ----
    #pragma unroll
    for (int it = 0; it < 8; ++it) {
        int idx = it * 512 + tid;
        int d = idx >> 4, p4 = idx & 15;
        int py = p4 >> 1, c4 = (p4 & 1) << 2;
        float4 v = *(const float4*)(xb + d * 65536 + py * 256 + c4);
        uint2 w; w.x = pack2(v.x, v.y); w.y = pack2(v.z, v.w);
        int bo = (d * 128 + (py * 8 + c4) * 2) ^ ((d & 7) << 4);
        *(uint2*)(Xs + bo) = w;
    }
    __syncthreads();

    // ---- phase 2: channel-LN stats ----
    {
        int n = l, dq = wv;
        float s = 0.f, s2 = 0.f;
        #pragma unroll
        for (int i2 = 0; i2 < 32; ++i2) {
            int d = dq * 32 + i2;
            float v = bf2f(*(const ushort_t*)(Xs + ((d * 128 + n * 2) ^ ((d & 7) << 4))));
            s += v; s2 += v * v;
        }
        red[dq * 64 + n] = s;
        red[512 + dq * 64 + n] = s2;
    }
    __syncthreads();
    if (tid < 64) {
        float s = 0.f, s2 = 0.f;
        #pragma unroll
        for (int q = 0; q < 8; ++q) { s += red[q * 64 + tid]; s2 += red[512 + q * 64 + tid]; }
        float mu = s * 0.00390625f;
        float var = s2 * 0.00390625f - mu * mu;
        muv[tid] = mu;
        muv[64 + tid] = rsqrtf(var + 1e-5f);
    }
    __syncthreads();

    // ---- normalize -> XN[n][d] bf16 (swizzled) ----
    {
        int n = l, dc = wv;
        float mu = muv[n], rs = muv[64 + n];
        #pragma unroll
        for (int jj = 0; jj < 4; ++jj) {
            int d0 = dc * 32 + jj * 8;
            uint_t p[4];
            #pragma unroll
            for (int h = 0; h < 4; ++h) {
                int da = d0 + 2 * h, db = d0 + 2 * h + 1;
                float va = bf2f(*(const ushort_t*)(Xs + ((da * 128 + n * 2) ^ ((da & 7) << 4))));
                float vb = bf2f(*(const ushort_t*)(Xs + ((db * 128 + n * 2) ^ ((db & 7) << 4))));
                float aa = (va - mu) * rs * gamw[da] + betw[da];
                float ab = (vb - mu) * rs * gamw[db] + betw[db];
                p[h] = pack2(aa, ab);
            }
            int bo = ((n << 9) + (d0 << 1));
            bo ^= ((bo >> 9) & 7) << 4;
            uint4 q4; q4.x = p[0]; q4.y = p[1]; q4.z = p[2]; q4.w = p[3];
            *(uint4*)(XNb + bo) = q4;
        }
    }
    __syncthreads();   // region0 (Xs) dead after this barrier -> reused as V

    const int srcA = (((2 * g) & 3) << 4) | m15;
    const int srcB = (((2 * g + 1) & 3) << 4) | m15;
    const bool hi = (g >= 2);
    F8 qf[4], kfr[4];

    // ---- pass A: Q+K rows for head wv (acc = 64 VGPRs) ----
    {
        f32x4 acc[4][4] = {};
        for (int kt = 0; kt < 8; ++kt) {
            short8 bfr[4];
            #pragma unroll
            for (int nt = 0; nt < 4; ++nt) {
                int bo = ((nt * 16 + m15) << 9) + kt * 64 + g * 16;
                bo ^= ((bo >> 9) & 7) << 4;
                bfr[nt] = *(const short8*)(XNb + bo);
            }
            #pragma unroll
            for (int mt = 0; mt < 4; ++mt) {
                short8 afr = *(const short8*)(wqkv + (wv * 96 + mt * 16 + m15) * 256 + kt * 32 + g * 8);
                #pragma unroll
                for (int nt = 0; nt < 4; ++nt)
                    acc[mt][nt] = MFMA16(afr, bfr[nt], acc[mt][nt]);
            }
        }
        // qf[t] elem q = Q[i=t*16+(l&15)][dh=(l>>4)*8+q]; kfr same for K. Regs only.
        build_frag(acc[0], acc[1], srcA, srcB, hi, qf);
        build_frag(acc[2], acc[3], srcA, srcB, hi, kfr);
    }

    char* Vsh = Xs + wv * 4096;   // [32 d][64 j] bf16, row 128 B, swz ^(d&7)<<4 (wave-private)

    // ---- pass B: V rows for head wv (acc = 32 VGPRs), scatter to LDS ----
    {
        f32x4 accv[2][4] = {};
        for (int kt = 0; kt < 8; ++kt) {
            short8 bfr[4];
            #pragma unroll
            for (int nt = 0; nt < 4; ++nt) {
                int bo = ((nt * 16 + m15) << 9) + kt * 64 + g * 16;
                bo ^= ((bo >> 9) & 7) << 4;
                bfr[nt] = *(const short8*)(XNb + bo);
            }
            #pragma unroll
            for (int mtv = 0; mtv < 2; ++mtv) {
                short8 afr = *(const short8*)(wqkv + (wv * 96 + 64 + mtv * 16 + m15) * 256 + kt * 32 + g * 8);
                #pragma unroll
                for (int nt = 0; nt < 4; ++nt)
                    accv[mtv][nt] = MFMA16(afr, bfr[nt], accv[mtv][nt]);
            }
        }
        #pragma unroll
        for (int mtv = 0; mtv < 2; ++mtv)
            #pragma unroll
            for (int nt = 0; nt < 4; ++nt)
                #pragma unroll
                for (int e = 0; e < 4; ++e) {
                    int d = mtv * 16 + g * 4 + e;
                    int bo = (d * 128 + (nt * 16 + m15) * 2) ^ ((d & 7) << 4);
                    *(ushort_t*)(Vsh + bo) = f2bf(accv[mtv][nt][e]);
                }
    }

    // ---- sim^T = K . Q^T : s[mts][nts] = C[j = mts*16+g*4+e][i = nts*16+m15] ----
    f32x4 s[4][4];
    #pragma unroll
    for (int mts = 0; mts < 4; ++mts)
        #pragma unroll
        for (int nts = 0; nts < 4; ++nts) {
            f32x4 z = {};
            s[mts][nts] = MFMA16(kfr[mts].v, qf[nts].v, z);
        }

    // ---- bias + softmax over j (j lives in regs (mts,e) x lane-groups g) ----
    #pragma unroll
    for (int nts = 0; nts < 4; ++nts) {
        const float* brp = biasR + l * 64 + nts * 16;
        float4 br0 = *(const float4*)(brp);
        float4 br1 = *(const float4*)(brp + 4);
        float4 br2 = *(const float4*)(brp + 8);
        float4 br3 = *(const float4*)(brp + 12);
        s[0][nts][0] += br0.x; s[0][nts][1] += br0.y; s[0][nts][2] += br0.z; s[0][nts][3] += br0.w;
        s[1][nts][0] += br1.x; s[1][nts][1] += br1.y; s[1][nts][2] += br1.z; s[1][nts][3] += br1.w;
        s[2][nts][0] += br2.x; s[2][nts][1] += br2.y; s[2][nts][2] += br2.z; s[2][nts][3] += br2.w;
        s[3][nts][0] += br3.x; s[3][nts][1] += br3.y; s[3][nts][2] += br3.z; s[3][nts][3] += br3.w;

        float mx = s[0][nts][0];
        #pragma unroll
        for (int mts = 0; mts < 4; ++mts)
            #pragma unroll
            for (int e = 0; e < 4; ++e) mx = fmaxf(mx, s[mts][nts][e]);
        mx = fmaxf(mx, __shfl_xor(mx, 16));
        mx = fmaxf(mx, __shfl_xor(mx, 32));
        float sum = 0.f;
        #pragma unroll
        for (int mts = 0; mts < 4; ++mts)
            #pragma unroll
            for (int e = 0; e < 4; ++e) {
                float p = __expf(s[mts][nts][e] - mx);
                s[mts][nts][e] = p; sum += p;
            }
        sum += __shfl_xor(sum, 16);
        sum += __shfl_xor(sum, 32);
        float inv = 1.f / sum;
        #pragma unroll
        for (int mts = 0; mts < 4; ++mts)
            #pragma unroll
            for (int e = 0; e < 4; ++e) s[mts][nts][e] *= inv;
    }

    // ---- PV: O^T[d][i] = sum_j V[d][j] * P[i][j] ----
    f32x4 o2[2][4] = {};
    #pragma unroll
    for (int ks = 0; ks < 2; ++ks) {
        // pb[t] elem q = P[i=t*16+(l&15)][j = ks*32+(l>>4)*8+q], from s rows ks*2, ks*2+1
        F8 pb[4];
        build_frag(s[ks * 2 + 0], s[ks * 2 + 1], srcA, srcB, hi, pb);
        #pragma unroll
        for (int mt2 = 0; mt2 < 2; ++mt2) {
            int d = mt2 * 16 + m15;
            int vo = (d * 128 + ks * 64 + g * 16) ^ ((d & 7) << 4);
            short8 va = *(const short8*)(Vsh + vo);
            #pragma unroll
            for (int t = 0; t < 4; ++t)
                o2[mt2][t] = MFMA16(va, pb[t].v, o2[mt2][t]);
        }
    }

    __syncthreads();   // all XN reads (pass B) done -> region1 becomes OT

    // write OT[i][o = wv*32 + d] bf16 into region1 (swizzled)
    #pragma unroll
    for (int mt2 = 0; mt2 < 2; ++mt2)
        #pragma unroll
        for (int t = 0; t < 4; ++t) {
            int i = t * 16 + m15;
            int dd = wv * 32 + mt2 * 16 + g * 4;
            int bo = (i << 9) + (dd << 1);
            bo ^= ((bo >> 9) & 7) << 4;
            uint2 pv;
            pv.x = pack2(o2[mt2][t][0], o2[mt2][t][1]);
            pv.y = pack2(o2[mt2][t][2], o2[mt2][t][3]);
            *(uint2*)(XNb + bo) = pv;
        }
    __syncthreads();

    // ---- phase 5: out projection + store ----
    {
        f32x4 po[2][4] = {};
        for (int kt = 0; kt < 8; ++kt) {
            short8 bfr[4];
            #pragma unroll
            for (int nt = 0; nt < 4; ++nt) {
                int bo = ((nt * 16 + m15) << 9) + kt * 64 + g * 16;
                bo ^= ((bo >> 9) & 7) << 4;
                bfr[nt] = *(const short8*)(XNb + bo);
            }
            #pragma unroll
            for (int mt = 0; mt < 2; ++mt) {
                short8 afr = *(const short8*)(wout + (wv * 32 + mt * 16 + m15) * 256 + kt * 32 + g * 8);
                #pragma unroll
                for (int nt = 0; nt < 4; ++nt)
                    po[mt][nt] = MFMA16(afr, bfr[nt], po[mt][nt]);
            }
        }
        float* ob = outp + xoff;
        #pragma unroll
        for (int mt = 0; mt < 2; ++mt) {
            int o0 = wv * 32 + mt * 16 + g * 4;
            float bo0 = boutp[o0], bo1 = boutp[o0 + 1], bo2 = boutp[o0 + 2], bo3 = boutp[o0 + 3];
            #pragma unroll
            for (int nt = 0; nt < 4; ++nt) {
                int i = nt * 16 + m15;
                int pix = (i >> 3) * 256 + (i & 7);
                ob[(o0 + 0) * 65536 + pix] = po[mt][nt][0] + bo0;
                ob[(o0 + 1) * 65536 + pix] = po[mt][nt][1] + bo1;
                ob[(o0 + 2) * 65536 + pix] = po[mt][nt][2] + bo2;
                ob[(o0 + 3) * 65536 + pix] = po[mt][nt][3] + bo3;
            }
        }
    }
}

// ---------------------------------------------------------------------------
extern "C" void kernel_launch(void* const* d_in, const int* in_sizes, int n_in,
                              void* d_out, int out_size, void* d_ws, size_t ws_size,
                              hipStream_t stream) {
    const float* x     = (const float*)d_in[0];
    const float* g     = (const float*)d_in[1];
    const float* b     = (const float*)d_in[2];
    const float* w_qkv = (const float*)d_in[3];
    const float* w_out = (const float*)d_in[4];
    const float* b_out = (const float*)d_in[5];
    const float* dw1 = (const float*)d_in[6],  *db1 = (const float*)d_in[7];
    const float* dg1 = (const float*)d_in[8],  *dbe1 = (const float*)d_in[9];
    const float* dw2 = (const float*)d_in[10], *db2 = (const float*)d_in[11];
    const float* dg2 = (const float*)d_in[12], *dbe2 = (const float*)d_in[13];
    const float* dw3 = (const float*)d_in[14], *db3 = (const float*)d_in[15];
    const float* dg3 = (const float*)d_in[16], *dbe3 = (const float*)d_in[17];
    const float* dw4 = (const float*)d_in[18], *db4 = (const float*)d_in[19];

    ushort_t* wbf   = (ushort_t*)d_ws;                         // 262144 bf16 = 524288 B
    float*    biasR = (float*)((char*)d_ws + 524288);          // 4096 f32   = 16384 B
    float*    valsg = (float*)((char*)d_ws + 540672);          // 289 f32

    hipLaunchKernelGGL(dpb_vals_kernel, dim3(37), dim3(512), 0, stream,
                       dw1, db1, dg1, dbe1, dw2, db2, dg2, dbe2,
                       dw3, db3, dg3, dbe3, dw4, db4, valsg);
    hipLaunchKernelGGL(cvt_kernel, dim3(520), dim3(512), 0, stream,
                       w_qkv, w_out, valsg, wbf, biasR);

    (void)hipFuncSetAttribute((const void*)win_attn,
                              hipFuncAttributeMaxDynamicSharedMemorySize, LDS_BYTES);
    hipLaunchKernelGGL(win_attn, dim3(2048), dim3(512), LDS_BYTES, stream,
                       x, g, b, wbf, wbf + 196608, b_out, biasR, (float*)d_out);
}